// Round 8
// baseline (564.814 us; speedup 1.0000x reference)
//
#include <hip/hip_runtime.h>
#include <hip/hip_bf16.h>

#define DEV static __device__ __forceinline__

typedef unsigned short u16;
typedef float fp32x4 __attribute__((ext_vector_type(4)));
typedef short bf16x8 __attribute__((ext_vector_type(8)));
typedef short bf16x4 __attribute__((ext_vector_type(4)));

DEV float bf2f(u16 u) { return __uint_as_float(((unsigned)u) << 16); }
DEV u16 f2bf(float f) {
  unsigned x = __float_as_uint(f);
  x += 0x7fffu + ((x >> 16) & 1u);
  return (u16)(x >> 16);
}

// packed f32x2 -> bf16x2 (low = a, high = b); no builtin on gfx950 (m240)
DEV unsigned cvt_pk_bf16(float a, float b) {
  unsigned r;
  asm("v_cvt_pk_bf16_f32 %0, %1, %2" : "=v"(r) : "v"(a), "v"(b));
  return r;
}

DEV void gload_lds16(const void* g, void* l) {
  __builtin_amdgcn_global_load_lds(
      (__attribute__((address_space(1))) void*)(unsigned long long)g,
      (__attribute__((address_space(3))) void*)(unsigned int)(unsigned long long)l,
      16, 0, 0);
}

// ---------------- fp32 -> bf16 convert (weights) ----------------
__global__ __launch_bounds__(256) void cvt_kernel(const float* __restrict__ in,
                                                  u16* __restrict__ out) {
  const int i = blockIdx.x * 256 + threadIdx.x;
  const fp32x4 v = ((const fp32x4*)in)[i];
  bf16x4 o;
#pragma unroll
  for (int j = 0; j < 4; j++) o[j] = (short)f2bf(v[j]);
  ((bf16x4*)out)[i] = o;
}

// ---------------- LayerNorm (ddof=1, eps added to std), fp32 in -> bf16 out --
__global__ __launch_bounds__(256) void ln_kernel(const float* __restrict__ x,
                                                 u16* __restrict__ y,
                                                 const float* __restrict__ gamma,
                                                 const float* __restrict__ beta) {
  const int row = blockIdx.x;
  const int t = threadIdx.x;
  const fp32x4 v = ((const fp32x4*)(x + (size_t)row * 1024))[t];
  float s = v[0] + v[1] + v[2] + v[3];
  float ss = v[0] * v[0] + v[1] * v[1] + v[2] * v[2] + v[3] * v[3];
#pragma unroll
  for (int o = 32; o > 0; o >>= 1) {
    s += __shfl_down(s, o);
    ss += __shfl_down(ss, o);
  }
  __shared__ float rs[4], rss[4];
  const int w = t >> 6;
  if ((t & 63) == 0) { rs[w] = s; rss[w] = ss; }
  __syncthreads();
  const float S = rs[0] + rs[1] + rs[2] + rs[3];
  const float SS = rss[0] + rss[1] + rss[2] + rss[3];
  const float mean = S * (1.0f / 1024.0f);
  const float var = fmaxf((SS - 1024.0f * mean * mean) * (1.0f / 1023.0f), 0.0f);
  const float sc = gamma[0] / (sqrtf(var) + 1e-6f);
  const float be = beta[0];
  bf16x4 o;
#pragma unroll
  for (int j = 0; j < 4; j++) o[j] = (short)f2bf((v[j] - mean) * sc + be);
  ((bf16x4*)(y + (size_t)row * 1024))[t] = o;
}

// ---------------- GEMM: C[M,N] = A[M,K] @ W[N,K]^T (m97 structure) ----------
// EPI: 0 = store bf16; 1 = bias+relu -> bf16; 2 = +resid -> fp32;
//      3 = bias+resid -> fp32; 4 = fused QKV split store (bf16 x3 buffers)
// Grid must have (gridDim.x*gridDim.y) % 8 == 0 (bijective XCD swizzle, m204).
template <int EPI>
__global__ __launch_bounds__(256, 2) void gemm_bt(
    const u16* __restrict__ A, const u16* __restrict__ W, u16* __restrict__ Cb,
    float* __restrict__ Cf, const float* __restrict__ bias,
    const float* __restrict__ resid, int M, int N, int K,
    u16* __restrict__ CbK, u16* __restrict__ CbV) {
  __shared__ u16 sA[128 * 32];
  __shared__ u16 sB[128 * 32];
  const int t = threadIdx.x;
  const int lane = t & 63;
  const int w = t >> 6;
  const int wr = (w >> 1) * 64;
  const int wc = (w & 1) * 64;
  const int lr = lane & 15;
  const int hi = lane >> 4;

  // XCD-aware block swizzle: XCD k processes a contiguous chunk of tiles.
  const int nwgx = gridDim.x;
  const int orig = blockIdx.y * nwgx + blockIdx.x;
  const int cpx = (nwgx * gridDim.y) >> 3;
  const int logical = (orig & 7) * cpx + (orig >> 3);
  const int bx = logical % nwgx, by = logical / nwgx;

  const u16* gA = A + (size_t)(by * 128 + (t >> 2)) * K + (t & 3) * 8;
  const u16* gB = W + (size_t)(bx * 128 + (t >> 2)) * K + (t & 3) * 8;
  const size_t rstep = (size_t)64 * K;
  u16* lA = &sA[t * 8];
  u16* lB = &sB[t * 8];

  const fp32x4 zero4 = {0.f, 0.f, 0.f, 0.f};
  fp32x4 acc[4][4];
#pragma unroll
  for (int i = 0; i < 4; i++)
#pragma unroll
    for (int j = 0; j < 4; j++) acc[i][j] = zero4;

  for (int k0 = 0; k0 < K; k0 += 32) {
    gload_lds16(gA, lA);
    gload_lds16(gA + rstep, lA + 2048);
    gload_lds16(gB, lB);
    gload_lds16(gB + rstep, lB + 2048);
    gA += 32;
    gB += 32;
    __syncthreads();
    bf16x8 af[4], bfr[4];
#pragma unroll
    for (int i = 0; i < 4; i++)
      af[i] = *(const bf16x8*)&sA[(wr + i * 16 + lr) * 32 + hi * 8];
#pragma unroll
    for (int j = 0; j < 4; j++)
      bfr[j] = *(const bf16x8*)&sB[(wc + j * 16 + lr) * 32 + hi * 8];
#pragma unroll
    for (int i = 0; i < 4; i++)
#pragma unroll
      for (int j = 0; j < 4; j++)
        acc[i][j] =
            __builtin_amdgcn_mfma_f32_16x16x32_bf16(af[i], bfr[j], acc[i][j], 0, 0, 0);
    __syncthreads();
  }

  const int row0 = by * 128 + wr + hi * 4;
  const int col0 = bx * 128 + wc + lr;
  float bj[4] = {0.f, 0.f, 0.f, 0.f};
  if (EPI == 1 || EPI == 3) {
#pragma unroll
    for (int j = 0; j < 4; j++) bj[j] = bias[col0 + j * 16];
  }
  // EPI==4: fused QKV. Block's 128-col span never crosses a 1024 boundary.
  u16* qkvDst = nullptr;
  int colL0 = 0;
  if (EPI == 4) {
    const int sel = col0 >> 10;
    qkvDst = (sel == 0) ? Cb : (sel == 1 ? CbK : CbV);
    colL0 = col0 & 1023;
  }
#pragma unroll
  for (int i = 0; i < 4; i++) {
#pragma unroll
    for (int r = 0; r < 4; r++) {
      const size_t row = (size_t)(row0 + i * 16 + r);
#pragma unroll
      for (int j = 0; j < 4; j++) {
        float v = acc[i][j][r];
        if (EPI == 4) {
          qkvDst[row * 1024 + colL0 + j * 16] = f2bf(v);
          continue;
        }
        const int col = col0 + j * 16;
        if (EPI == 1) v = fmaxf(v + bj[j], 0.f);
        if (EPI == 3) v += bj[j];
        if (EPI >= 2) {
          v += resid[row * N + col];
          Cf[row * N + col] = v;
        } else {
          Cb[row * N + col] = f2bf(v);
        }
      }
    }
  }
}

// ---------------- V transpose: V[b,s,h*64+d] -> VT[(b*16+h)*64+d][s] ---------
__global__ __launch_bounds__(256) void vtrans_kernel(const u16* __restrict__ V,
                                                     u16* __restrict__ VT) {
  const int st = blockIdx.x;  // s-tile (S/64)
  const int h = blockIdx.y;
  const int b = blockIdx.z;
  const int t = threadIdx.x;
  const int r = t >> 2, c0 = (t & 3) * 16;
  __shared__ u16 sT[64][72];

  const u16* src = V + ((size_t)(b * 2048 + st * 64 + r)) * 1024 + h * 64 + c0;
  bf16x8 v0 = *(const bf16x8*)src;
  bf16x8 v1 = *(const bf16x8*)(src + 8);
  const int cb = c0 ^ ((r >> 4) << 4);  // swizzled column base (16B granular)
  *(bf16x8*)&sT[r][cb] = v0;
  *(bf16x8*)&sT[r][cb + 8] = v1;
  __syncthreads();

  const int dc = r ^ ((c0 >> 4) << 4);  // swizzled column for logical col d=r
  bf16x8 o0, o1;
#pragma unroll
  for (int i = 0; i < 8; i++) o0[i] = sT[c0 + i][dc];
#pragma unroll
  for (int i = 0; i < 8; i++) o1[i] = sT[c0 + 8 + i][dc];
  u16* dst = VT + ((size_t)((b * 16 + h) * 64 + r)) * 2048 + st * 64 + c0;
  *(bf16x8*)dst = o0;
  *(bf16x8*)(dst + 8) = o1;
}

// ---------------- Flash attention (64 q-rows/block, 64-k tiles) -------------
// Swapped operands: S^T = K*Q^T, O^T = V^T*P^T. V pre-transposed globally and
// read DIRECTLY from L2 in PV (no sVT staging: V is L2-resident per XCD swizzle;
// guide m169 / Common-mistake #7). V loads issued early (T14), consumed after
// softmax. Defer-max (T13, THR=11 in exp2 domain) skips most O-rescales.
__global__ __launch_bounds__(256, 2) void attn_kernel(const u16* __restrict__ Q,
                                                      const u16* __restrict__ K,
                                                      const u16* __restrict__ VT,
                                                      u16* __restrict__ O) {
  // bijective XCD swizzle: XCD k gets 8 consecutive (h,b) groups -> K/V 4MB in L2
  const int orig = blockIdx.x + 32 * (blockIdx.y + 16 * blockIdx.z);
  const int logical = (orig & 7) * 256 + (orig >> 3);
  const int qt = logical & 31;
  const int h = (logical >> 5) & 15;
  const int b = logical >> 9;

  const int t = threadIdx.x, lane = t & 63, w = t >> 6;
  const int lr = lane & 15, hi = lane >> 4;

  __shared__ u16 sK[64][72];
  __shared__ u16 sQP[64][72];  // Q tile, then per-wave P rows [q][k]

  const size_t base = ((size_t)b * 2048) * 1024 + (size_t)h * 64;
  const size_t vbase = (((size_t)b * 16 + h) * 64) * 2048;
  const int r = t >> 2, c0 = (t & 3) * 16;

  { // Q stage, scaled by 0.125*log2(e) for exp2-domain softmax
    const float qs = 0.125f * 1.44269504f;
    const u16* src = Q + base + (size_t)(qt * 64 + r) * 1024 + c0;
    bf16x8 u0 = *(const bf16x8*)src;
    bf16x8 u1 = *(const bf16x8*)(src + 8);
    union { unsigned u[4]; bf16x8 v; } q0, q1;
#pragma unroll
    for (int j = 0; j < 4; j++)
      q0.u[j] = cvt_pk_bf16(bf2f((u16)u0[2 * j]) * qs, bf2f((u16)u0[2 * j + 1]) * qs);
#pragma unroll
    for (int j = 0; j < 4; j++)
      q1.u[j] = cvt_pk_bf16(bf2f((u16)u1[2 * j]) * qs, bf2f((u16)u1[2 * j + 1]) * qs);
    *(bf16x8*)&sQP[r][c0] = q0.v;
    *(bf16x8*)&sQP[r][c0 + 8] = q1.v;
  }
  __syncthreads();
  const int qrow = w * 16 + lr;
  bf16x8 qreg0 = *(const bf16x8*)&sQP[qrow][hi * 8];
  bf16x8 qreg1 = *(const bf16x8*)&sQP[qrow][32 + hi * 8];

  // per-lane V^T fragment base: row df*16+lr, col hi*8 (+ kt*64 + ks*32)
  const u16* vrow0 = VT + vbase + (size_t)lr * 2048 + hi * 8;

  // prefetch k-tile 0 into registers
  bf16x8 kA, kB;
  {
    const u16* ks = K + base + (size_t)r * 1024 + c0;
    kA = *(const bf16x8*)ks;
    kB = *(const bf16x8*)(ks + 8);
  }

  const fp32x4 zero4 = {0.f, 0.f, 0.f, 0.f};
  fp32x4 onT[4];
#pragma unroll
  for (int df = 0; df < 4; df++) onT[df] = zero4;
  float mrun = -1e30f, lrun = 0.f;

  for (int kt = 0; kt < 32; ++kt) {
    __syncthreads();  // prev tile's compute done (qreg reads done too)
    *(bf16x8*)&sK[r][c0] = kA;
    *(bf16x8*)&sK[r][c0 + 8] = kB;
    __syncthreads();
    if (kt < 31) {  // prefetch next K tile; latency hides under compute
      const u16* kn = K + base + (size_t)((kt + 1) * 64 + r) * 1024 + c0;
      kA = *(const bf16x8*)kn;
      kB = *(const bf16x8*)(kn + 8);
    }
    // issue THIS tile's V^T fragment loads early (L2-resident; consumed in PV)
    bf16x8 vf[4][2];
#pragma unroll
    for (int df = 0; df < 4; df++)
#pragma unroll
      for (int ks = 0; ks < 2; ks++)
        vf[df][ks] =
            *(const bf16x8*)(vrow0 + (size_t)df * 16 * 2048 + kt * 64 + ks * 32);

    // S^T tile: C[k][q] (exp2 domain); wave w owns q rows [w*16, w*16+16)
    fp32x4 sc[4];
    __builtin_amdgcn_s_setprio(1);
#pragma unroll
    for (int kk = 0; kk < 4; kk++) {
      fp32x4 a = zero4;
      bf16x8 kf0 = *(const bf16x8*)&sK[kk * 16 + lr][hi * 8];
      bf16x8 kf1 = *(const bf16x8*)&sK[kk * 16 + lr][32 + hi * 8];
      a = __builtin_amdgcn_mfma_f32_16x16x32_bf16(kf0, qreg0, a, 0, 0, 0);
      a = __builtin_amdgcn_mfma_f32_16x16x32_bf16(kf1, qreg1, a, 0, 0, 0);
      sc[kk] = a;
    }
    __builtin_amdgcn_s_setprio(0);

    // online softmax (base-2); lane's q = qrow, holds k = kt*64+kk*16+hi*4+rr
    float m0 = fmaxf(fmaxf(sc[0][0], sc[0][1]), fmaxf(sc[0][2], sc[0][3]));
    float m1 = fmaxf(fmaxf(sc[1][0], sc[1][1]), fmaxf(sc[1][2], sc[1][3]));
    float m2 = fmaxf(fmaxf(sc[2][0], sc[2][1]), fmaxf(sc[2][2], sc[2][3]));
    float m3 = fmaxf(fmaxf(sc[3][0], sc[3][1]), fmaxf(sc[3][2], sc[3][3]));
    float mloc = fmaxf(fmaxf(m0, m1), fmaxf(m2, m3));
    mloc = fmaxf(mloc, __shfl_xor(mloc, 16));
    mloc = fmaxf(mloc, __shfl_xor(mloc, 32));
    // T13 defer-max: only rescale when the max moved materially (wave-uniform)
    if (!__all(mloc - mrun <= 11.0f)) {
      const float mnew = fmaxf(mrun, mloc);
      const float alpha = exp2f(mrun - mnew);
      lrun *= alpha;
#pragma unroll
      for (int df = 0; df < 4; df++) onT[df] *= alpha;
      mrun = mnew;
    }
    float psum = 0.f;
#pragma unroll
    for (int kk = 0; kk < 4; kk++) {
      float p0 = exp2f(sc[kk][0] - mrun), p1 = exp2f(sc[kk][1] - mrun);
      float p2 = exp2f(sc[kk][2] - mrun), p3 = exp2f(sc[kk][3] - mrun);
      psum += (p0 + p1) + (p2 + p3);
      uint2 pk = {cvt_pk_bf16(p0, p1), cvt_pk_bf16(p2, p3)};
      *(uint2*)&sQP[qrow][kk * 16 + hi * 4] = pk;  // wave-private P row
    }
    psum += __shfl_xor(psum, 16);
    psum += __shfl_xor(psum, 32);
    lrun += psum;

    // O^T += V^T * P^T  (P from LDS, V from regs loaded out of L2)
    __builtin_amdgcn_s_setprio(1);
#pragma unroll
    for (int df = 0; df < 4; df++) {
#pragma unroll
      for (int ks = 0; ks < 2; ks++) {
        bf16x8 pf = *(const bf16x8*)&sQP[qrow][ks * 32 + hi * 8];
        onT[df] = __builtin_amdgcn_mfma_f32_16x16x32_bf16(vf[df][ks], pf, onT[df], 0, 0, 0);
      }
    }
    __builtin_amdgcn_s_setprio(0);
  }

  const float invl = 1.0f / lrun;
  u16* dst = O + base + (size_t)(qt * 64 + qrow) * 1024;
#pragma unroll
  for (int df = 0; df < 4; df++) {
    uint2 o2 = {cvt_pk_bf16(onT[df][0] * invl, onT[df][1] * invl),
                cvt_pk_bf16(onT[df][2] * invl, onT[df][3] * invl)};
    *(uint2*)&dst[df * 16 + hi * 4] = o2;
  }
}

extern "C" void kernel_launch(void* const* d_in, const int* in_sizes, int n_in,
                              void* d_out, int out_size, void* d_ws, size_t ws_size,
                              hipStream_t stream) {
  const float* x = (const float*)d_in[0];
  // d_in[1] = src_mask (unused by reference semantics)
  const float* wq = (const float*)d_in[2];
  const float* wk = (const float*)d_in[3];
  const float* wv = (const float*)d_in[4];
  const float* wo = (const float*)d_in[5];
  const float* w1 = (const float*)d_in[6];
  const float* b1 = (const float*)d_in[7];
  const float* w2 = (const float*)d_in[8];
  const float* b2 = (const float*)d_in[9];
  const float* g1 = (const float*)d_in[10];
  const float* be1 = (const float*)d_in[11];
  const float* g2 = (const float*)d_in[12];
  const float* be2 = (const float*)d_in[13];
  float* out = (float*)d_out;

  const size_t MB = 1024ull * 1024ull;
  char* ws = (char*)d_ws;
  if (ws_size < 136 * MB) return;  // fail loudly (output stays zero)

  u16* wqkv = (u16*)(ws + 0 * MB);  // [3072][1024]: wq | wk | wv contiguous
  u16* wqb = (u16*)(ws + 0 * MB);
  u16* wkb = (u16*)(ws + 2 * MB);
  u16* wvb = (u16*)(ws + 4 * MB);
  u16* wob = (u16*)(ws + 6 * MB);
  u16* w1b = (u16*)(ws + 8 * MB);
  u16* w2b = (u16*)(ws + 16 * MB);
  u16* Qb = (u16*)(ws + 24 * MB);
  u16* Kb = (u16*)(ws + 40 * MB);
  u16* Vb = (u16*)(ws + 56 * MB);
  u16* Ctx = (u16*)(ws + 72 * MB);
  u16* Hb = (u16*)(ws + 24 * MB);  // reuses Q/K/V/Ctx (dead by FFN1)
  u16* Yb = (u16*)(ws + 88 * MB);  // LN output; also VT home (disjoint lifetimes)
  u16* VTb = (u16*)(ws + 88 * MB); // VT alive only between vtrans and attn
  float* X2 = (float*)(ws + 104 * MB);

  dim3 blk(256);

  cvt_kernel<<<1024, blk, 0, stream>>>(wq, wqb);
  cvt_kernel<<<1024, blk, 0, stream>>>(wk, wkb);
  cvt_kernel<<<1024, blk, 0, stream>>>(wv, wvb);
  cvt_kernel<<<1024, blk, 0, stream>>>(wo, wob);
  cvt_kernel<<<4096, blk, 0, stream>>>(w1, w1b);
  cvt_kernel<<<4096, blk, 0, stream>>>(w2, w2b);

  ln_kernel<<<8192, blk, 0, stream>>>(x, Yb, g1, be1);

  // fused QKV: one GEMM, N=3072, split-store epilogue
  gemm_bt<4><<<dim3(24, 64), blk, 0, stream>>>(Yb, wqkv, Qb, nullptr, nullptr, nullptr,
                                               8192, 3072, 1024, Kb, Vb);
  // Yb (LN1 output) dead from here; VTb overlays it.
  vtrans_kernel<<<dim3(32, 16, 4), blk, 0, stream>>>(Vb, VTb);

  attn_kernel<<<dim3(32, 16, 4), blk, 0, stream>>>(Qb, Kb, VTb, Ctx);

  gemm_bt<2><<<dim3(8, 64), blk, 0, stream>>>(Ctx, wob, nullptr, X2, nullptr, x, 8192,
                                              1024, 1024, nullptr, nullptr);

  ln_kernel<<<8192, blk, 0, stream>>>(X2, Yb, g2, be2);

  gemm_bt<1><<<dim3(32, 64), blk, 0, stream>>>(Yb, w1b, Hb, nullptr, b1, nullptr, 8192,
                                               4096, 1024, nullptr, nullptr);

  gemm_bt<3><<<dim3(8, 64), blk, 0, stream>>>(Hb, w2b, nullptr, out, b2, X2, 8192, 1024,
                                              4096, nullptr, nullptr);
}

// Round 9
// 459.028 us; speedup vs baseline: 1.2305x; 1.2305x over previous
//
#include <hip/hip_runtime.h>
#include <hip/hip_bf16.h>

#define DEV static __device__ __forceinline__

typedef unsigned short u16;
typedef float fp32x4 __attribute__((ext_vector_type(4)));
typedef short bf16x8 __attribute__((ext_vector_type(8)));
typedef short bf16x4 __attribute__((ext_vector_type(4)));

DEV float bf2f(u16 u) { return __uint_as_float(((unsigned)u) << 16); }
DEV u16 f2bf(float f) {
  unsigned x = __float_as_uint(f);
  x += 0x7fffu + ((x >> 16) & 1u);
  return (u16)(x >> 16);
}

// packed f32x2 -> bf16x2 (low = a, high = b); no builtin on gfx950 (m240)
DEV unsigned cvt_pk_bf16(float a, float b) {
  unsigned r;
  asm("v_cvt_pk_bf16_f32 %0, %1, %2" : "=v"(r) : "v"(a), "v"(b));
  return r;
}

DEV void gload_lds16(const void* g, void* l) {
  __builtin_amdgcn_global_load_lds(
      (__attribute__((address_space(1))) void*)(unsigned long long)g,
      (__attribute__((address_space(3))) void*)(unsigned int)(unsigned long long)l,
      16, 0, 0);
}

// ---------------- fp32 -> bf16 convert (weights) ----------------
__global__ __launch_bounds__(256) void cvt_kernel(const float* __restrict__ in,
                                                  u16* __restrict__ out) {
  const int i = blockIdx.x * 256 + threadIdx.x;
  const fp32x4 v = ((const fp32x4*)in)[i];
  bf16x4 o;
#pragma unroll
  for (int j = 0; j < 4; j++) o[j] = (short)f2bf(v[j]);
  ((bf16x4*)out)[i] = o;
}

// ---------------- LayerNorm (ddof=1, eps added to std), fp32 in -> bf16 out --
__global__ __launch_bounds__(256) void ln_kernel(const float* __restrict__ x,
                                                 u16* __restrict__ y,
                                                 const float* __restrict__ gamma,
                                                 const float* __restrict__ beta) {
  const int row = blockIdx.x;
  const int t = threadIdx.x;
  const fp32x4 v = ((const fp32x4*)(x + (size_t)row * 1024))[t];
  float s = v[0] + v[1] + v[2] + v[3];
  float ss = v[0] * v[0] + v[1] * v[1] + v[2] * v[2] + v[3] * v[3];
#pragma unroll
  for (int o = 32; o > 0; o >>= 1) {
    s += __shfl_down(s, o);
    ss += __shfl_down(ss, o);
  }
  __shared__ float rs[4], rss[4];
  const int w = t >> 6;
  if ((t & 63) == 0) { rs[w] = s; rss[w] = ss; }
  __syncthreads();
  const float S = rs[0] + rs[1] + rs[2] + rs[3];
  const float SS = rss[0] + rss[1] + rss[2] + rss[3];
  const float mean = S * (1.0f / 1024.0f);
  const float var = fmaxf((SS - 1024.0f * mean * mean) * (1.0f / 1023.0f), 0.0f);
  const float sc = gamma[0] / (sqrtf(var) + 1e-6f);
  const float be = beta[0];
  bf16x4 o;
#pragma unroll
  for (int j = 0; j < 4; j++) o[j] = (short)f2bf((v[j] - mean) * sc + be);
  ((bf16x4*)(y + (size_t)row * 1024))[t] = o;
}

// ---------------- GEMM: C[M,N] = A[M,K] @ W[N,K]^T (m97 structure) ----------
// EPI: 0 = store bf16; 1 = bias+relu -> bf16; 2 = +resid -> fp32;
//      3 = bias+resid -> fp32; 4 = fused QKV split store (bf16 x3 buffers)
// Grid must have (gridDim.x*gridDim.y) % 8 == 0 (bijective XCD swizzle, m204).
template <int EPI>
__global__ __launch_bounds__(256, 2) void gemm_bt(
    const u16* __restrict__ A, const u16* __restrict__ W, u16* __restrict__ Cb,
    float* __restrict__ Cf, const float* __restrict__ bias,
    const float* __restrict__ resid, int M, int N, int K,
    u16* __restrict__ CbK, u16* __restrict__ CbV) {
  __shared__ u16 sA[128 * 32];
  __shared__ u16 sB[128 * 32];
  const int t = threadIdx.x;
  const int lane = t & 63;
  const int w = t >> 6;
  const int wr = (w >> 1) * 64;
  const int wc = (w & 1) * 64;
  const int lr = lane & 15;
  const int hi = lane >> 4;

  // XCD-aware block swizzle: XCD k processes a contiguous chunk of tiles.
  const int nwgx = gridDim.x;
  const int orig = blockIdx.y * nwgx + blockIdx.x;
  const int cpx = (nwgx * gridDim.y) >> 3;
  const int logical = (orig & 7) * cpx + (orig >> 3);
  const int bx = logical % nwgx, by = logical / nwgx;

  const u16* gA = A + (size_t)(by * 128 + (t >> 2)) * K + (t & 3) * 8;
  const u16* gB = W + (size_t)(bx * 128 + (t >> 2)) * K + (t & 3) * 8;
  const size_t rstep = (size_t)64 * K;
  u16* lA = &sA[t * 8];
  u16* lB = &sB[t * 8];

  const fp32x4 zero4 = {0.f, 0.f, 0.f, 0.f};
  fp32x4 acc[4][4];
#pragma unroll
  for (int i = 0; i < 4; i++)
#pragma unroll
    for (int j = 0; j < 4; j++) acc[i][j] = zero4;

  for (int k0 = 0; k0 < K; k0 += 32) {
    gload_lds16(gA, lA);
    gload_lds16(gA + rstep, lA + 2048);
    gload_lds16(gB, lB);
    gload_lds16(gB + rstep, lB + 2048);
    gA += 32;
    gB += 32;
    __syncthreads();
    bf16x8 af[4], bfr[4];
#pragma unroll
    for (int i = 0; i < 4; i++)
      af[i] = *(const bf16x8*)&sA[(wr + i * 16 + lr) * 32 + hi * 8];
#pragma unroll
    for (int j = 0; j < 4; j++)
      bfr[j] = *(const bf16x8*)&sB[(wc + j * 16 + lr) * 32 + hi * 8];
#pragma unroll
    for (int i = 0; i < 4; i++)
#pragma unroll
      for (int j = 0; j < 4; j++)
        acc[i][j] =
            __builtin_amdgcn_mfma_f32_16x16x32_bf16(af[i], bfr[j], acc[i][j], 0, 0, 0);
    __syncthreads();
  }

  const int row0 = by * 128 + wr + hi * 4;
  const int col0 = bx * 128 + wc + lr;
  float bj[4] = {0.f, 0.f, 0.f, 0.f};
  if (EPI == 1 || EPI == 3) {
#pragma unroll
    for (int j = 0; j < 4; j++) bj[j] = bias[col0 + j * 16];
  }
  // EPI==4: fused QKV. Block's 128-col span never crosses a 1024 boundary.
  u16* qkvDst = nullptr;
  int colL0 = 0;
  if (EPI == 4) {
    const int sel = col0 >> 10;
    qkvDst = (sel == 0) ? Cb : (sel == 1 ? CbK : CbV);
    colL0 = col0 & 1023;
  }
#pragma unroll
  for (int i = 0; i < 4; i++) {
#pragma unroll
    for (int r = 0; r < 4; r++) {
      const size_t row = (size_t)(row0 + i * 16 + r);
#pragma unroll
      for (int j = 0; j < 4; j++) {
        float v = acc[i][j][r];
        if (EPI == 4) {
          qkvDst[row * 1024 + colL0 + j * 16] = f2bf(v);
          continue;
        }
        const int col = col0 + j * 16;
        if (EPI == 1) v = fmaxf(v + bj[j], 0.f);
        if (EPI == 3) v += bj[j];
        if (EPI >= 2) {
          v += resid[row * N + col];
          Cf[row * N + col] = v;
        } else {
          Cb[row * N + col] = f2bf(v);
        }
      }
    }
  }
}

// ---------------- V transpose: V[b,s,h*64+d] -> VT[(b*16+h)*64+d][s] ---------
__global__ __launch_bounds__(256) void vtrans_kernel(const u16* __restrict__ V,
                                                     u16* __restrict__ VT) {
  const int st = blockIdx.x;  // s-tile (S/64)
  const int h = blockIdx.y;
  const int b = blockIdx.z;
  const int t = threadIdx.x;
  const int r = t >> 2, c0 = (t & 3) * 16;
  __shared__ u16 sT[64][72];

  const u16* src = V + ((size_t)(b * 2048 + st * 64 + r)) * 1024 + h * 64 + c0;
  bf16x8 v0 = *(const bf16x8*)src;
  bf16x8 v1 = *(const bf16x8*)(src + 8);
  const int cb = c0 ^ ((r >> 4) << 4);  // swizzled column base (16B granular)
  *(bf16x8*)&sT[r][cb] = v0;
  *(bf16x8*)&sT[r][cb + 8] = v1;
  __syncthreads();

  const int dc = r ^ ((c0 >> 4) << 4);  // swizzled column for logical col d=r
  bf16x8 o0, o1;
#pragma unroll
  for (int i = 0; i < 8; i++) o0[i] = sT[c0 + i][dc];
#pragma unroll
  for (int i = 0; i < 8; i++) o1[i] = sT[c0 + 8 + i][dc];
  u16* dst = VT + ((size_t)((b * 16 + h) * 64 + r)) * 2048 + st * 64 + c0;
  *(bf16x8*)dst = o0;
  *(bf16x8*)(dst + 8) = o1;
}

// ---------------- Flash attention (64 q-rows/block, 64-k tiles) -------------
// R7 structure (proven 156us): 256 thr, stride-72 LDS, LDS-staged K AND V^T,
// Q hoisted to regs, reg-prefetch of next K/VT tile, setprio around MFMA,
// XCD swizzle. R8 keepers: defer-max (T13, THR=11 exp2-domain), fmax tree.
__global__ __launch_bounds__(256, 2) void attn_kernel(const u16* __restrict__ Q,
                                                      const u16* __restrict__ K,
                                                      const u16* __restrict__ VT,
                                                      u16* __restrict__ O) {
  // bijective XCD swizzle: XCD k gets 8 consecutive (h,b) groups -> K/V 4MB in L2
  const int orig = blockIdx.x + 32 * (blockIdx.y + 16 * blockIdx.z);
  const int logical = (orig & 7) * 256 + (orig >> 3);
  const int qt = logical & 31;
  const int h = (logical >> 5) & 15;
  const int b = logical >> 9;

  const int t = threadIdx.x, lane = t & 63, w = t >> 6;
  const int lr = lane & 15, hi = lane >> 4;

  __shared__ u16 sK[64][72];
  __shared__ u16 sVT[64][72];  // V^T tile: [d][kv]
  __shared__ u16 sQP[64][72];  // Q tile, then per-wave P rows [q][k]

  const size_t base = ((size_t)b * 2048) * 1024 + (size_t)h * 64;
  const size_t vbase = (((size_t)b * 16 + h) * 64) * 2048;
  const int r = t >> 2, c0 = (t & 3) * 16;

  { // Q stage, scaled by 0.125*log2(e) for exp2-domain softmax
    const float qs = 0.125f * 1.44269504f;
    const u16* src = Q + base + (size_t)(qt * 64 + r) * 1024 + c0;
    bf16x8 u0 = *(const bf16x8*)src;
    bf16x8 u1 = *(const bf16x8*)(src + 8);
    union { unsigned u[4]; bf16x8 v; } q0, q1;
#pragma unroll
    for (int j = 0; j < 4; j++)
      q0.u[j] = cvt_pk_bf16(bf2f((u16)u0[2 * j]) * qs, bf2f((u16)u0[2 * j + 1]) * qs);
#pragma unroll
    for (int j = 0; j < 4; j++)
      q1.u[j] = cvt_pk_bf16(bf2f((u16)u1[2 * j]) * qs, bf2f((u16)u1[2 * j + 1]) * qs);
    *(bf16x8*)&sQP[r][c0] = q0.v;
    *(bf16x8*)&sQP[r][c0 + 8] = q1.v;
  }
  __syncthreads();
  const int qrow = w * 16 + lr;
  bf16x8 qreg0 = *(const bf16x8*)&sQP[qrow][hi * 8];
  bf16x8 qreg1 = *(const bf16x8*)&sQP[qrow][32 + hi * 8];

  // prefetch k-tile 0 into registers
  bf16x8 kA, kB, vA, vB;
  {
    const u16* ks = K + base + (size_t)r * 1024 + c0;
    kA = *(const bf16x8*)ks;
    kB = *(const bf16x8*)(ks + 8);
    const u16* vs = VT + vbase + (size_t)r * 2048 + c0;
    vA = *(const bf16x8*)vs;
    vB = *(const bf16x8*)(vs + 8);
  }

  const fp32x4 zero4 = {0.f, 0.f, 0.f, 0.f};
  fp32x4 onT[4];
#pragma unroll
  for (int df = 0; df < 4; df++) onT[df] = zero4;
  float mrun = -1e30f, lrun = 0.f;

  for (int kt = 0; kt < 32; ++kt) {
    __syncthreads();  // prev tile's compute done (qreg reads done too)
    *(bf16x8*)&sK[r][c0] = kA;
    *(bf16x8*)&sK[r][c0 + 8] = kB;
    *(bf16x8*)&sVT[r][c0] = vA;
    *(bf16x8*)&sVT[r][c0 + 8] = vB;
    __syncthreads();
    if (kt < 31) {  // issue next tile's loads; latency hides under compute
      const u16* kn = K + base + (size_t)((kt + 1) * 64 + r) * 1024 + c0;
      kA = *(const bf16x8*)kn;
      kB = *(const bf16x8*)(kn + 8);
      const u16* vn = VT + vbase + (size_t)r * 2048 + (kt + 1) * 64 + c0;
      vA = *(const bf16x8*)vn;
      vB = *(const bf16x8*)(vn + 8);
    }

    // S^T tile: C[k][q] (exp2 domain); wave w owns q rows [w*16, w*16+16)
    fp32x4 sc[4];
    __builtin_amdgcn_s_setprio(1);
#pragma unroll
    for (int kk = 0; kk < 4; kk++) {
      fp32x4 a = zero4;
      bf16x8 kf0 = *(const bf16x8*)&sK[kk * 16 + lr][hi * 8];
      bf16x8 kf1 = *(const bf16x8*)&sK[kk * 16 + lr][32 + hi * 8];
      a = __builtin_amdgcn_mfma_f32_16x16x32_bf16(kf0, qreg0, a, 0, 0, 0);
      a = __builtin_amdgcn_mfma_f32_16x16x32_bf16(kf1, qreg1, a, 0, 0, 0);
      sc[kk] = a;
    }
    __builtin_amdgcn_s_setprio(0);

    // online softmax (base-2); lane's q = qrow, holds k = kt*64+kk*16+hi*4+rr
    float m0 = fmaxf(fmaxf(sc[0][0], sc[0][1]), fmaxf(sc[0][2], sc[0][3]));
    float m1 = fmaxf(fmaxf(sc[1][0], sc[1][1]), fmaxf(sc[1][2], sc[1][3]));
    float m2 = fmaxf(fmaxf(sc[2][0], sc[2][1]), fmaxf(sc[2][2], sc[2][3]));
    float m3 = fmaxf(fmaxf(sc[3][0], sc[3][1]), fmaxf(sc[3][2], sc[3][3]));
    float mloc = fmaxf(fmaxf(m0, m1), fmaxf(m2, m3));
    mloc = fmaxf(mloc, __shfl_xor(mloc, 16));
    mloc = fmaxf(mloc, __shfl_xor(mloc, 32));
    // T13 defer-max: rescale only when the max moved materially (wave-uniform)
    if (!__all(mloc - mrun <= 11.0f)) {
      const float mnew = fmaxf(mrun, mloc);
      const float alpha = exp2f(mrun - mnew);
      lrun *= alpha;
#pragma unroll
      for (int df = 0; df < 4; df++) onT[df] *= alpha;
      mrun = mnew;
    }
    float psum = 0.f;
#pragma unroll
    for (int kk = 0; kk < 4; kk++) {
      float p0 = exp2f(sc[kk][0] - mrun), p1 = exp2f(sc[kk][1] - mrun);
      float p2 = exp2f(sc[kk][2] - mrun), p3 = exp2f(sc[kk][3] - mrun);
      psum += (p0 + p1) + (p2 + p3);
      uint2 pk = {cvt_pk_bf16(p0, p1), cvt_pk_bf16(p2, p3)};
      *(uint2*)&sQP[qrow][kk * 16 + hi * 4] = pk;  // wave-private P row
    }
    psum += __shfl_xor(psum, 16);
    psum += __shfl_xor(psum, 32);
    lrun += psum;

    // O^T += V^T * P^T  (same-wave LDS write->read is in-order)
    __builtin_amdgcn_s_setprio(1);
#pragma unroll
    for (int df = 0; df < 4; df++) {
#pragma unroll
      for (int ks = 0; ks < 2; ks++) {
        bf16x8 vf = *(const bf16x8*)&sVT[df * 16 + lr][ks * 32 + hi * 8];
        bf16x8 pf = *(const bf16x8*)&sQP[qrow][ks * 32 + hi * 8];
        onT[df] = __builtin_amdgcn_mfma_f32_16x16x32_bf16(vf, pf, onT[df], 0, 0, 0);
      }
    }
    __builtin_amdgcn_s_setprio(0);
  }

  const float invl = 1.0f / lrun;
  u16* dst = O + base + (size_t)(qt * 64 + qrow) * 1024;
#pragma unroll
  for (int df = 0; df < 4; df++) {
    uint2 o2 = {cvt_pk_bf16(onT[df][0] * invl, onT[df][1] * invl),
                cvt_pk_bf16(onT[df][2] * invl, onT[df][3] * invl)};
    *(uint2*)&dst[df * 16 + hi * 4] = o2;
  }
}

extern "C" void kernel_launch(void* const* d_in, const int* in_sizes, int n_in,
                              void* d_out, int out_size, void* d_ws, size_t ws_size,
                              hipStream_t stream) {
  const float* x = (const float*)d_in[0];
  // d_in[1] = src_mask (unused by reference semantics)
  const float* wq = (const float*)d_in[2];
  const float* wk = (const float*)d_in[3];
  const float* wv = (const float*)d_in[4];
  const float* wo = (const float*)d_in[5];
  const float* w1 = (const float*)d_in[6];
  const float* b1 = (const float*)d_in[7];
  const float* w2 = (const float*)d_in[8];
  const float* b2 = (const float*)d_in[9];
  const float* g1 = (const float*)d_in[10];
  const float* be1 = (const float*)d_in[11];
  const float* g2 = (const float*)d_in[12];
  const float* be2 = (const float*)d_in[13];
  float* out = (float*)d_out;

  const size_t MB = 1024ull * 1024ull;
  char* ws = (char*)d_ws;
  if (ws_size < 136 * MB) return;  // fail loudly (output stays zero)

  u16* wqkv = (u16*)(ws + 0 * MB);  // [3072][1024]: wq | wk | wv contiguous
  u16* wqb = (u16*)(ws + 0 * MB);
  u16* wkb = (u16*)(ws + 2 * MB);
  u16* wvb = (u16*)(ws + 4 * MB);
  u16* wob = (u16*)(ws + 6 * MB);
  u16* w1b = (u16*)(ws + 8 * MB);
  u16* w2b = (u16*)(ws + 16 * MB);
  u16* Qb = (u16*)(ws + 24 * MB);
  u16* Kb = (u16*)(ws + 40 * MB);
  u16* Vb = (u16*)(ws + 56 * MB);
  u16* Ctx = (u16*)(ws + 72 * MB);
  u16* Hb = (u16*)(ws + 24 * MB);  // reuses Q/K/V/Ctx (dead by FFN1)
  u16* Yb = (u16*)(ws + 88 * MB);  // LN output; also VT home (disjoint lifetimes)
  u16* VTb = (u16*)(ws + 88 * MB); // VT alive only between vtrans and attn
  float* X2 = (float*)(ws + 104 * MB);

  dim3 blk(256);

  cvt_kernel<<<1024, blk, 0, stream>>>(wq, wqb);
  cvt_kernel<<<1024, blk, 0, stream>>>(wk, wkb);
  cvt_kernel<<<1024, blk, 0, stream>>>(wv, wvb);
  cvt_kernel<<<1024, blk, 0, stream>>>(wo, wob);
  cvt_kernel<<<4096, blk, 0, stream>>>(w1, w1b);
  cvt_kernel<<<4096, blk, 0, stream>>>(w2, w2b);

  ln_kernel<<<8192, blk, 0, stream>>>(x, Yb, g1, be1);

  // fused QKV: one GEMM, N=3072, split-store epilogue (saves 2 extra A reads)
  gemm_bt<4><<<dim3(24, 64), blk, 0, stream>>>(Yb, wqkv, Qb, nullptr, nullptr, nullptr,
                                               8192, 3072, 1024, Kb, Vb);
  // Yb (LN1 output) dead from here; VTb overlays it.
  vtrans_kernel<<<dim3(32, 16, 4), blk, 0, stream>>>(Vb, VTb);

  attn_kernel<<<dim3(32, 16, 4), blk, 0, stream>>>(Qb, Kb, VTb, Ctx);

  gemm_bt<2><<<dim3(8, 64), blk, 0, stream>>>(Ctx, wob, nullptr, X2, nullptr, x, 8192,
                                              1024, 1024, nullptr, nullptr);

  ln_kernel<<<8192, blk, 0, stream>>>(X2, Yb, g2, be2);

  gemm_bt<1><<<dim3(32, 64), blk, 0, stream>>>(Yb, w1b, Hb, nullptr, b1, nullptr, 8192,
                                               4096, 1024, nullptr, nullptr);

  gemm_bt<3><<<dim3(8, 64), blk, 0, stream>>>(Hb, w2b, nullptr, out, b2, X2, 8192, 1024,
                                              4096, nullptr, nullptr);
}

// Round 11
// 451.158 us; speedup vs baseline: 1.2519x; 1.0174x over previous
//
#include <hip/hip_runtime.h>
#include <hip/hip_bf16.h>

#define DEV static __device__ __forceinline__

typedef unsigned short u16;
typedef float fp32x4 __attribute__((ext_vector_type(4)));
typedef short bf16x8 __attribute__((ext_vector_type(8)));
typedef short bf16x4 __attribute__((ext_vector_type(4)));

DEV float bf2f(u16 u) { return __uint_as_float(((unsigned)u) << 16); }
DEV u16 f2bf(float f) {
  unsigned x = __float_as_uint(f);
  x += 0x7fffu + ((x >> 16) & 1u);
  return (u16)(x >> 16);
}

// packed f32x2 -> bf16x2 (low = a, high = b); no builtin on gfx950 (m240)
DEV unsigned cvt_pk_bf16(float a, float b) {
  unsigned r;
  asm("v_cvt_pk_bf16_f32 %0, %1, %2" : "=v"(r) : "v"(a), "v"(b));
  return r;
}

DEV void gload_lds16(const void* g, void* l) {
  __builtin_amdgcn_global_load_lds(
      (__attribute__((address_space(1))) void*)(unsigned long long)g,
      (__attribute__((address_space(3))) void*)(unsigned int)(unsigned long long)l,
      16, 0, 0);
}

// ---------------- fp32 -> bf16 convert (weights) ----------------
__global__ __launch_bounds__(256) void cvt_kernel(const float* __restrict__ in,
                                                  u16* __restrict__ out) {
  const int i = blockIdx.x * 256 + threadIdx.x;
  const fp32x4 v = ((const fp32x4*)in)[i];
  bf16x4 o;
#pragma unroll
  for (int j = 0; j < 4; j++) o[j] = (short)f2bf(v[j]);
  ((bf16x4*)out)[i] = o;
}

// ---------------- LayerNorm (ddof=1, eps added to std), fp32 in -> bf16 out --
__global__ __launch_bounds__(256) void ln_kernel(const float* __restrict__ x,
                                                 u16* __restrict__ y,
                                                 const float* __restrict__ gamma,
                                                 const float* __restrict__ beta) {
  const int row = blockIdx.x;
  const int t = threadIdx.x;
  const fp32x4 v = ((const fp32x4*)(x + (size_t)row * 1024))[t];
  float s = v[0] + v[1] + v[2] + v[3];
  float ss = v[0] * v[0] + v[1] * v[1] + v[2] * v[2] + v[3] * v[3];
#pragma unroll
  for (int o = 32; o > 0; o >>= 1) {
    s += __shfl_down(s, o);
    ss += __shfl_down(ss, o);
  }
  __shared__ float rs[4], rss[4];
  const int w = t >> 6;
  if ((t & 63) == 0) { rs[w] = s; rss[w] = ss; }
  __syncthreads();
  const float S = rs[0] + rs[1] + rs[2] + rs[3];
  const float SS = rss[0] + rss[1] + rss[2] + rss[3];
  const float mean = S * (1.0f / 1024.0f);
  const float var = fmaxf((SS - 1024.0f * mean * mean) * (1.0f / 1023.0f), 0.0f);
  const float sc = gamma[0] / (sqrtf(var) + 1e-6f);
  const float be = beta[0];
  bf16x4 o;
#pragma unroll
  for (int j = 0; j < 4; j++) o[j] = (short)f2bf((v[j] - mean) * sc + be);
  ((bf16x4*)(y + (size_t)row * 1024))[t] = o;
}

// ---------------- GEMM: C[M,N] = A[M,K] @ W[N,K]^T (m97 structure) ----------
// EPI: 0 = store bf16; 1 = bias+relu -> bf16; 2 = +resid -> fp32;
//      3 = bias+resid -> fp32; 4 = fused QKV split store (bf16 x3 buffers)
// Grid must have (gridDim.x*gridDim.y) % 8 == 0 (bijective XCD swizzle, m204).
template <int EPI>
__global__ __launch_bounds__(256, 2) void gemm_bt(
    const u16* __restrict__ A, const u16* __restrict__ W, u16* __restrict__ Cb,
    float* __restrict__ Cf, const float* __restrict__ bias,
    const float* __restrict__ resid, int M, int N, int K,
    u16* __restrict__ CbK, u16* __restrict__ CbV) {
  __shared__ u16 sA[128 * 32];
  __shared__ u16 sB[128 * 32];
  const int t = threadIdx.x;
  const int lane = t & 63;
  const int w = t >> 6;
  const int wr = (w >> 1) * 64;
  const int wc = (w & 1) * 64;
  const int lr = lane & 15;
  const int hi = lane >> 4;

  // XCD-aware block swizzle: XCD k processes a contiguous chunk of tiles.
  const int nwgx = gridDim.x;
  const int orig = blockIdx.y * nwgx + blockIdx.x;
  const int cpx = (nwgx * gridDim.y) >> 3;
  const int logical = (orig & 7) * cpx + (orig >> 3);
  const int bx = logical % nwgx, by = logical / nwgx;

  const u16* gA = A + (size_t)(by * 128 + (t >> 2)) * K + (t & 3) * 8;
  const u16* gB = W + (size_t)(bx * 128 + (t >> 2)) * K + (t & 3) * 8;
  const size_t rstep = (size_t)64 * K;
  u16* lA = &sA[t * 8];
  u16* lB = &sB[t * 8];

  const fp32x4 zero4 = {0.f, 0.f, 0.f, 0.f};
  fp32x4 acc[4][4];
#pragma unroll
  for (int i = 0; i < 4; i++)
#pragma unroll
    for (int j = 0; j < 4; j++) acc[i][j] = zero4;

  for (int k0 = 0; k0 < K; k0 += 32) {
    gload_lds16(gA, lA);
    gload_lds16(gA + rstep, lA + 2048);
    gload_lds16(gB, lB);
    gload_lds16(gB + rstep, lB + 2048);
    gA += 32;
    gB += 32;
    __syncthreads();
    bf16x8 af[4], bfr[4];
#pragma unroll
    for (int i = 0; i < 4; i++)
      af[i] = *(const bf16x8*)&sA[(wr + i * 16 + lr) * 32 + hi * 8];
#pragma unroll
    for (int j = 0; j < 4; j++)
      bfr[j] = *(const bf16x8*)&sB[(wc + j * 16 + lr) * 32 + hi * 8];
#pragma unroll
    for (int i = 0; i < 4; i++)
#pragma unroll
      for (int j = 0; j < 4; j++)
        acc[i][j] =
            __builtin_amdgcn_mfma_f32_16x16x32_bf16(af[i], bfr[j], acc[i][j], 0, 0, 0);
    __syncthreads();
  }

  const int row0 = by * 128 + wr + hi * 4;
  const int col0 = bx * 128 + wc + lr;
  float bj[4] = {0.f, 0.f, 0.f, 0.f};
  if (EPI == 1 || EPI == 3) {
#pragma unroll
    for (int j = 0; j < 4; j++) bj[j] = bias[col0 + j * 16];
  }
  // EPI==4: fused QKV. Block's 128-col span never crosses a 1024 boundary.
  u16* qkvDst = nullptr;
  int colL0 = 0;
  if (EPI == 4) {
    const int sel = col0 >> 10;
    qkvDst = (sel == 0) ? Cb : (sel == 1 ? CbK : CbV);
    colL0 = col0 & 1023;
  }
#pragma unroll
  for (int i = 0; i < 4; i++) {
#pragma unroll
    for (int r = 0; r < 4; r++) {
      const size_t row = (size_t)(row0 + i * 16 + r);
#pragma unroll
      for (int j = 0; j < 4; j++) {
        float v = acc[i][j][r];
        if (EPI == 4) {
          qkvDst[row * 1024 + colL0 + j * 16] = f2bf(v);
          continue;
        }
        const int col = col0 + j * 16;
        if (EPI == 1) v = fmaxf(v + bj[j], 0.f);
        if (EPI == 3) v += bj[j];
        if (EPI >= 2) {
          v += resid[row * N + col];
          Cf[row * N + col] = v;
        } else {
          Cb[row * N + col] = f2bf(v);
        }
      }
    }
  }
}

// ---------------- V transpose: V[b,s,h*64+d] -> VT[(b*16+h)*64+d][s] ---------
__global__ __launch_bounds__(256) void vtrans_kernel(const u16* __restrict__ V,
                                                     u16* __restrict__ VT) {
  const int st = blockIdx.x;  // s-tile (S/64)
  const int h = blockIdx.y;
  const int b = blockIdx.z;
  const int t = threadIdx.x;
  const int r = t >> 2, c0 = (t & 3) * 16;
  __shared__ u16 sT[64][72];

  const u16* src = V + ((size_t)(b * 2048 + st * 64 + r)) * 1024 + h * 64 + c0;
  bf16x8 v0 = *(const bf16x8*)src;
  bf16x8 v1 = *(const bf16x8*)(src + 8);
  const int cb = c0 ^ ((r >> 4) << 4);  // swizzled column base (16B granular)
  *(bf16x8*)&sT[r][cb] = v0;
  *(bf16x8*)&sT[r][cb + 8] = v1;
  __syncthreads();

  const int dc = r ^ ((c0 >> 4) << 4);  // swizzled column for logical col d=r
  bf16x8 o0, o1;
#pragma unroll
  for (int i = 0; i < 8; i++) o0[i] = sT[c0 + i][dc];
#pragma unroll
  for (int i = 0; i < 8; i++) o1[i] = sT[c0 + 8 + i][dc];
  u16* dst = VT + ((size_t)((b * 16 + h) * 64 + r)) * 2048 + st * 64 + c0;
  *(bf16x8*)dst = o0;
  *(bf16x8*)(dst + 8) = o1;
}

// ---------------- Flash attention (64 q-rows/block, 64-k tiles) -------------
// R9 structure + NEW: linear [64][64] LDS tiles with chunk-XOR swizzle
// (chunk ^= row&7; G4 fix — rows are 128B so banks are row-invariant, the XOR
// spreads each 16-row fragment read over 8 distinct 16B slots -> 2-way = free).
// Applied consistently on write AND read side of all three tiles.
// Also: lrun cross-lane reduction deferred to epilogue (alpha is wave-uniform).
DEV int swz(int row, int chunk) { return row * 64 + ((chunk ^ (row & 7)) << 3); }

__global__ __launch_bounds__(256, 2) void attn_kernel(const u16* __restrict__ Q,
                                                      const u16* __restrict__ K,
                                                      const u16* __restrict__ VT,
                                                      u16* __restrict__ O) {
  // bijective XCD swizzle: XCD k gets 8 consecutive (h,b) groups -> K/V 4MB in L2
  const int orig = blockIdx.x + 32 * (blockIdx.y + 16 * blockIdx.z);
  const int logical = (orig & 7) * 256 + (orig >> 3);
  const int qt = logical & 31;
  const int h = (logical >> 5) & 15;
  const int b = logical >> 9;

  const int t = threadIdx.x, lane = t & 63, w = t >> 6;
  const int lr = lane & 15, hi = lane >> 4;

  __shared__ u16 sK[64 * 64];
  __shared__ u16 sVT[64 * 64];  // V^T tile: [d][kv]
  __shared__ u16 sQP[64 * 64];  // Q tile, then per-wave P rows [q][k]

  const size_t base = ((size_t)b * 2048) * 1024 + (size_t)h * 64;
  const size_t vbase = (((size_t)b * 16 + h) * 64) * 2048;
  const int r = t >> 2, c0 = (t & 3) * 16;
  const int wch = (t & 3) * 2;  // this thread's chunk pair for staging

  { // Q stage, scaled by 0.125*log2(e) for exp2-domain softmax
    const float qs = 0.125f * 1.44269504f;
    const u16* src = Q + base + (size_t)(qt * 64 + r) * 1024 + c0;
    bf16x8 u0 = *(const bf16x8*)src;
    bf16x8 u1 = *(const bf16x8*)(src + 8);
    union { unsigned u[4]; bf16x8 v; } q0, q1;
#pragma unroll
    for (int j = 0; j < 4; j++)
      q0.u[j] = cvt_pk_bf16(bf2f((u16)u0[2 * j]) * qs, bf2f((u16)u0[2 * j + 1]) * qs);
#pragma unroll
    for (int j = 0; j < 4; j++)
      q1.u[j] = cvt_pk_bf16(bf2f((u16)u1[2 * j]) * qs, bf2f((u16)u1[2 * j + 1]) * qs);
    *(bf16x8*)&sQP[swz(r, wch)] = q0.v;
    *(bf16x8*)&sQP[swz(r, wch + 1)] = q1.v;
  }
  __syncthreads();
  const int qrow = w * 16 + lr;
  bf16x8 qreg0 = *(const bf16x8*)&sQP[swz(qrow, hi)];
  bf16x8 qreg1 = *(const bf16x8*)&sQP[swz(qrow, 4 + hi)];

  // prefetch k-tile 0 into registers
  bf16x8 kA, kB, vA, vB;
  {
    const u16* ks = K + base + (size_t)r * 1024 + c0;
    kA = *(const bf16x8*)ks;
    kB = *(const bf16x8*)(ks + 8);
    const u16* vs = VT + vbase + (size_t)r * 2048 + c0;
    vA = *(const bf16x8*)vs;
    vB = *(const bf16x8*)(vs + 8);
  }

  const fp32x4 zero4 = {0.f, 0.f, 0.f, 0.f};
  fp32x4 onT[4];
#pragma unroll
  for (int df = 0; df < 4; df++) onT[df] = zero4;
  float mrun = -1e30f, lrun = 0.f;  // lrun is a per-lane partial (reduced at end)

  for (int kt = 0; kt < 32; ++kt) {
    __syncthreads();  // prev tile's compute done (qreg reads done too)
    *(bf16x8*)&sK[swz(r, wch)] = kA;
    *(bf16x8*)&sK[swz(r, wch + 1)] = kB;
    *(bf16x8*)&sVT[swz(r, wch)] = vA;
    *(bf16x8*)&sVT[swz(r, wch + 1)] = vB;
    __syncthreads();
    if (kt < 31) {  // issue next tile's loads; latency hides under compute
      const u16* kn = K + base + (size_t)((kt + 1) * 64 + r) * 1024 + c0;
      kA = *(const bf16x8*)kn;
      kB = *(const bf16x8*)(kn + 8);
      const u16* vn = VT + vbase + (size_t)r * 2048 + (kt + 1) * 64 + c0;
      vA = *(const bf16x8*)vn;
      vB = *(const bf16x8*)(vn + 8);
    }

    // S^T tile: C[k][q] (exp2 domain); wave w owns q rows [w*16, w*16+16)
    fp32x4 sc[4];
    __builtin_amdgcn_s_setprio(1);
#pragma unroll
    for (int kk = 0; kk < 4; kk++) {
      fp32x4 a = zero4;
      bf16x8 kf0 = *(const bf16x8*)&sK[swz(kk * 16 + lr, hi)];
      bf16x8 kf1 = *(const bf16x8*)&sK[swz(kk * 16 + lr, 4 + hi)];
      a = __builtin_amdgcn_mfma_f32_16x16x32_bf16(kf0, qreg0, a, 0, 0, 0);
      a = __builtin_amdgcn_mfma_f32_16x16x32_bf16(kf1, qreg1, a, 0, 0, 0);
      sc[kk] = a;
    }
    __builtin_amdgcn_s_setprio(0);

    // online softmax (base-2); lane's q = qrow, holds k = kt*64+kk*16+hi*4+rr
    float m0 = fmaxf(fmaxf(sc[0][0], sc[0][1]), fmaxf(sc[0][2], sc[0][3]));
    float m1 = fmaxf(fmaxf(sc[1][0], sc[1][1]), fmaxf(sc[1][2], sc[1][3]));
    float m2 = fmaxf(fmaxf(sc[2][0], sc[2][1]), fmaxf(sc[2][2], sc[2][3]));
    float m3 = fmaxf(fmaxf(sc[3][0], sc[3][1]), fmaxf(sc[3][2], sc[3][3]));
    float mloc = fmaxf(fmaxf(m0, m1), fmaxf(m2, m3));
    mloc = fmaxf(mloc, __shfl_xor(mloc, 16));
    mloc = fmaxf(mloc, __shfl_xor(mloc, 32));
    // T13 defer-max: rescale only when the max moved materially (wave-uniform)
    if (!__all(mloc - mrun <= 11.0f)) {
      const float mnew = fmaxf(mrun, mloc);
      const float alpha = exp2f(mrun - mnew);
      lrun *= alpha;
#pragma unroll
      for (int df = 0; df < 4; df++) onT[df] *= alpha;
      mrun = mnew;
    }
#pragma unroll
    for (int kk = 0; kk < 4; kk++) {
      float p0 = exp2f(sc[kk][0] - mrun), p1 = exp2f(sc[kk][1] - mrun);
      float p2 = exp2f(sc[kk][2] - mrun), p3 = exp2f(sc[kk][3] - mrun);
      lrun += (p0 + p1) + (p2 + p3);
      uint2 pk = {cvt_pk_bf16(p0, p1), cvt_pk_bf16(p2, p3)};
      // 8B write at 4-elem offset within chunk 2*kk + (hi>>1)
      *(uint2*)&sQP[swz(qrow, 2 * kk + (hi >> 1)) + (hi & 1) * 4] = pk;
    }

    // O^T += V^T * P^T  (same-wave LDS write->read is in-order)
    __builtin_amdgcn_s_setprio(1);
#pragma unroll
    for (int df = 0; df < 4; df++) {
#pragma unroll
      for (int ks = 0; ks < 2; ks++) {
        bf16x8 vf = *(const bf16x8*)&sVT[swz(df * 16 + lr, ks * 4 + hi)];
        bf16x8 pf = *(const bf16x8*)&sQP[swz(qrow, ks * 4 + hi)];
        onT[df] = __builtin_amdgcn_mfma_f32_16x16x32_bf16(vf, pf, onT[df], 0, 0, 0);
      }
    }
    __builtin_amdgcn_s_setprio(0);
  }

  // epilogue: reduce per-lane lrun partials across the 4 hi-groups
  lrun += __shfl_xor(lrun, 16);
  lrun += __shfl_xor(lrun, 32);
  const float invl = 1.0f / lrun;
  u16* dst = O + base + (size_t)(qt * 64 + qrow) * 1024;
#pragma unroll
  for (int df = 0; df < 4; df++) {
    uint2 o2 = {cvt_pk_bf16(onT[df][0] * invl, onT[df][1] * invl),
                cvt_pk_bf16(onT[df][2] * invl, onT[df][3] * invl)};
    *(uint2*)&dst[df * 16 + hi * 4] = o2;
  }
}

extern "C" void kernel_launch(void* const* d_in, const int* in_sizes, int n_in,
                              void* d_out, int out_size, void* d_ws, size_t ws_size,
                              hipStream_t stream) {
  const float* x = (const float*)d_in[0];
  // d_in[1] = src_mask (unused by reference semantics)
  const float* wq = (const float*)d_in[2];
  const float* wk = (const float*)d_in[3];
  const float* wv = (const float*)d_in[4];
  const float* wo = (const float*)d_in[5];
  const float* w1 = (const float*)d_in[6];
  const float* b1 = (const float*)d_in[7];
  const float* w2 = (const float*)d_in[8];
  const float* b2 = (const float*)d_in[9];
  const float* g1 = (const float*)d_in[10];
  const float* be1 = (const float*)d_in[11];
  const float* g2 = (const float*)d_in[12];
  const float* be2 = (const float*)d_in[13];
  float* out = (float*)d_out;

  const size_t MB = 1024ull * 1024ull;
  char* ws = (char*)d_ws;
  if (ws_size < 136 * MB) return;  // fail loudly (output stays zero)

  u16* wqkv = (u16*)(ws + 0 * MB);  // [3072][1024]: wq | wk | wv contiguous
  u16* wqb = (u16*)(ws + 0 * MB);
  u16* wkb = (u16*)(ws + 2 * MB);
  u16* wvb = (u16*)(ws + 4 * MB);
  u16* wob = (u16*)(ws + 6 * MB);
  u16* w1b = (u16*)(ws + 8 * MB);
  u16* w2b = (u16*)(ws + 16 * MB);
  u16* Qb = (u16*)(ws + 24 * MB);
  u16* Kb = (u16*)(ws + 40 * MB);
  u16* Vb = (u16*)(ws + 56 * MB);
  u16* Ctx = (u16*)(ws + 72 * MB);
  u16* Hb = (u16*)(ws + 24 * MB);  // reuses Q/K/V/Ctx (dead by FFN1)
  u16* Yb = (u16*)(ws + 88 * MB);  // LN output; also VT home (disjoint lifetimes)
  u16* VTb = (u16*)(ws + 88 * MB); // VT alive only between vtrans and attn
  float* X2 = (float*)(ws + 104 * MB);

  dim3 blk(256);

  cvt_kernel<<<1024, blk, 0, stream>>>(wq, wqb);
  cvt_kernel<<<1024, blk, 0, stream>>>(wk, wkb);
  cvt_kernel<<<1024, blk, 0, stream>>>(wv, wvb);
  cvt_kernel<<<1024, blk, 0, stream>>>(wo, wob);
  cvt_kernel<<<4096, blk, 0, stream>>>(w1, w1b);
  cvt_kernel<<<4096, blk, 0, stream>>>(w2, w2b);

  ln_kernel<<<8192, blk, 0, stream>>>(x, Yb, g1, be1);

  // fused QKV: one GEMM, N=3072, split-store epilogue (saves 2 extra A reads)
  gemm_bt<4><<<dim3(24, 64), blk, 0, stream>>>(Yb, wqkv, Qb, nullptr, nullptr, nullptr,
                                               8192, 3072, 1024, Kb, Vb);
  // Yb (LN1 output) dead from here; VTb overlays it.
  vtrans_kernel<<<dim3(32, 16, 4), blk, 0, stream>>>(Vb, VTb);

  attn_kernel<<<dim3(32, 16, 4), blk, 0, stream>>>(Qb, Kb, VTb, Ctx);

  gemm_bt<2><<<dim3(8, 64), blk, 0, stream>>>(Ctx, wob, nullptr, X2, nullptr, x, 8192,
                                              1024, 1024, nullptr, nullptr);

  ln_kernel<<<8192, blk, 0, stream>>>(X2, Yb, g2, be2);

  gemm_bt<1><<<dim3(32, 64), blk, 0, stream>>>(Yb, w1b, Hb, nullptr, b1, nullptr, 8192,
                                               4096, 1024, nullptr, nullptr);

  gemm_bt<3><<<dim3(8, 64), blk, 0, stream>>>(Hb, w2b, nullptr, out, b2, X2, 8192, 1024,
                                              4096, nullptr, nullptr);
}